// Round 4
// baseline (73.543 us; speedup 1.0000x reference)
//
#include <hip/hip_runtime.h>

#define D 2
#define DH 5
#define NH 3
#define NW0 (DH*D)          // 10
#define NWS (NH*DH*DH)      // 75
#define NWO (D*DH)          // 10
#define NWTOT (NW0+NWS+NWO) // 95

// c = 2*log2(e): weights pre-scaled by c so exp2 needs no argument mul.
#define C_SCALE   2.8853900817779268f
#define K03_OVER_C 0.10397207708399180f  // 0.3/c
#define K28_OVER_C 0.97040605462392273f  // 2.8/c
#define LN2        0.69314718055994531f

// Given z' = c*z and r = 1/(2^{z'}+1) = 1/(e^{2z}+1):
//   h  = 0.3 z + 0.7 - 1.4 r          (true act value)
//   d' = d/c = 0.3/c + (2.8/c)(r-r^2) (scaled act-derivative)
__device__ __forceinline__ void act_core(float zp, float& h, float& dp) {
    float e = __builtin_amdgcn_exp2f(zp);
    float r = __builtin_amdgcn_rcpf(e + 1.0f);
    float u = fmaf(-r, r, r);                       // r - r^2
    dp = fmaf(K28_OVER_C, u, K03_OVER_C);
    h  = fmaf(-1.4f, r, fmaf(K03_OVER_C, zp, 0.7f));
}

// Pre-scale all weights by c into workspace (runs every launch; deterministic).
__global__ void prescale_kernel(const float* __restrict__ gW0,
                                const float* __restrict__ gWs,
                                const float* __restrict__ gWout,
                                float* __restrict__ wsf) {
    int i = threadIdx.x;
    if (i < NW0)            wsf[i] = C_SCALE * gW0[i];
    else if (i < NW0+NWS)   wsf[i] = C_SCALE * gWs[i - NW0];
    else if (i < NWTOT)     wsf[i] = C_SCALE * gWout[i - NW0 - NWS];
}

__global__ __launch_bounds__(256, 8) void nnflow_kernel(
    const float4* __restrict__ xj4,
    const float* __restrict__ wsf,
    float4* __restrict__ out4,
    int nquads)
{
    int t = blockIdx.x * blockDim.x + threadIdx.x;
    if (t >= nquads) return;

    // ---- scaled weights: uniform address + const idx -> scalar loads ----
    float w0[DH][D];
    #pragma unroll
    for (int k = 0; k < DH; ++k)
        #pragma unroll
        for (int j = 0; j < D; ++j)
            w0[k][j] = wsf[k * D + j];

    float ws[NH][DH][DH];
    #pragma unroll
    for (int i = 0; i < NH; ++i)
        #pragma unroll
        for (int k = 0; k < DH; ++k)
            #pragma unroll
            for (int j = 0; j < DH; ++j)
                ws[i][k][j] = wsf[NW0 + (i * DH + k) * DH + j];

    float wo[D][DH];
    #pragma unroll
    for (int r = 0; r < D; ++r)
        #pragma unroll
        for (int j = 0; j < DH; ++j)
            wo[r][j] = wsf[NW0 + NWS + r * DH + j];

    // ---- 4 samples = 3 float4, coalesced ----
    float4 v0 = xj4[(size_t)t * 3 + 0];
    float4 v1 = xj4[(size_t)t * 3 + 1];
    float4 v2 = xj4[(size_t)t * 3 + 2];

    float xs[4][3] = {
        {v0.x, v0.y, v0.z},
        {v0.w, v1.x, v1.y},
        {v1.z, v1.w, v2.x},
        {v2.y, v2.z, v2.w}
    };
    float os[4][3];

    #pragma unroll
    for (int s = 0; s < 4; ++s) {
        float x0 = xs[s][0], x1 = xs[s][1], lj = xs[s][2];

        // ---- layer 0: z' = cW0 x ; J = d'[k] * w0'[k][:]  (== d*W0 exactly)
        float h[DH], J0[DH], J1[DH];
        #pragma unroll
        for (int k = 0; k < DH; ++k) {
            float zp = fmaf(w0[k][0], x0, w0[k][1] * x1);
            float hk, dk;
            act_core(zp, hk, dk);
            h[k]  = hk;
            J0[k] = dk * w0[k][0];
            J1[k] = dk * w0[k][1];
        }

        // ---- hidden layers: J <- d' * (W' J) == d * (W J)
        #pragma unroll
        for (int i = 0; i < NH; ++i) {
            float hn[DH], Jn0[DH], Jn1[DH];
            #pragma unroll
            for (int k = 0; k < DH; ++k) {
                float zp = 0.f, j0 = 0.f, j1 = 0.f;
                #pragma unroll
                for (int j = 0; j < DH; ++j) {
                    float w = ws[i][k][j];
                    zp = fmaf(w, h[j],  zp);
                    j0 = fmaf(w, J0[j], j0);
                    j1 = fmaf(w, J1[j], j1);
                }
                float hk, dk;
                act_core(zp, hk, dk);
                hn[k]  = hk;
                Jn0[k] = dk * j0;
                Jn1[k] = dk * j1;
            }
            #pragma unroll
            for (int k = 0; k < DH; ++k) { h[k] = hn[k]; J0[k] = Jn0[k]; J1[k] = Jn1[k]; }
        }

        // ---- output layer: det = d0'*d1'*cross(jo) == true det (c^2 cancels)
        float y[2], dp[2], jo0[2], jo1[2];
        #pragma unroll
        for (int r = 0; r < 2; ++r) {
            float zp = 0.f, j0 = 0.f, j1 = 0.f;
            #pragma unroll
            for (int j = 0; j < DH; ++j) {
                float w = wo[r][j];
                zp = fmaf(w, h[j],  zp);
                j0 = fmaf(w, J0[j], j0);
                j1 = fmaf(w, J1[j], j1);
            }
            float yk, dk;
            act_core(zp, yk, dk);
            y[r] = yk; dp[r] = dk;
            jo0[r] = j0; jo1[r] = j1;
        }

        float cross = fmaf(-jo1[0], jo0[1], jo0[0] * jo1[1]);
        float det   = (dp[0] * dp[1]) * cross;
        float lg    = __builtin_amdgcn_logf(fabsf(det));
        os[s][0] = y[0];
        os[s][1] = y[1];
        os[s][2] = fmaf(LN2, lg, lj);
    }

    out4[(size_t)t * 3 + 0] = make_float4(os[0][0], os[0][1], os[0][2], os[1][0]);
    out4[(size_t)t * 3 + 1] = make_float4(os[1][1], os[1][2], os[2][0], os[2][1]);
    out4[(size_t)t * 3 + 2] = make_float4(os[2][2], os[3][0], os[3][1], os[3][2]);
}

extern "C" void kernel_launch(void* const* d_in, const int* in_sizes, int n_in,
                              void* d_out, int out_size, void* d_ws, size_t ws_size,
                              hipStream_t stream) {
    const float* xj   = (const float*)d_in[0];
    const float* W0   = (const float*)d_in[1];
    const float* Ws   = (const float*)d_in[2];
    const float* Wout = (const float*)d_in[3];
    float* out = (float*)d_out;
    float* wsf = (float*)d_ws;

    prescale_kernel<<<1, 128, 0, stream>>>(W0, Ws, Wout, wsf);

    int n = in_sizes[0] / (D + 1);   // 4194304
    int nquads = n / 4;

    dim3 block(256);
    dim3 grid((nquads + block.x - 1) / block.x);
    nnflow_kernel<<<grid, block, 0, stream>>>(
        (const float4*)xj, wsf, (float4*)out, nquads);
}

// Round 7
// 54.423 us; speedup vs baseline: 1.3513x; 1.3513x over previous
//
#include <hip/hip_runtime.h>

typedef float v2f __attribute__((ext_vector_type(2)));

#define D 2
#define DH 5
#define NH 3
#define NW0 (DH*D)            // 10
#define NWS (NH*DH*DH)        // 75
#define NWTOT (NW0+NWS+D*DH)  // 95

// c = 2*log2(e): weights pre-scaled so exp2 needs no argument mul.
#define C_SCALE 2.8853900817779268f
#define K03C 0.10397207708399180f   // 0.3/c
#define K28C 0.97040605462392273f   // 2.8/c
#define LN2  0.69314718055994531f

__device__ __forceinline__ v2f splat(float x){ return (v2f)(x); }
__device__ __forceinline__ v2f vfma(v2f a, v2f b, v2f c){
    return __builtin_elementwise_fma(a, b, c);   // -> v_pk_fma_f32 (gfx90a+)
}

// Packed activation: z' = c*z for a sample-pair;
//   r = 1/(2^{z'}+1);  h = 0.3z+0.7-1.4r;  d' = 0.3/c + (2.8/c)(r-r^2)
__device__ __forceinline__ void act2(v2f zp, v2f& h, v2f& dp) {
    v2f e, r;
    e.x = __builtin_amdgcn_exp2f(zp.x);
    e.y = __builtin_amdgcn_exp2f(zp.y);
    v2f a = e + splat(1.0f);
    r.x = __builtin_amdgcn_rcpf(a.x);
    r.y = __builtin_amdgcn_rcpf(a.y);
    v2f u = vfma(-r, r, r);                      // r - r^2
    dp = vfma(splat(K28C), u, splat(K03C));
    h  = vfma(splat(-1.4f), r, vfma(splat(K03C), zp, splat(0.7f)));
}

// Pre-scale all weights by c into workspace (deterministic, every launch).
__global__ void prescale_kernel(const float* __restrict__ gW0,
                                const float* __restrict__ gWs,
                                const float* __restrict__ gWout,
                                float* __restrict__ wsf) {
    int i = threadIdx.x;
    if (i < NW0)            wsf[i] = C_SCALE * gW0[i];
    else if (i < NW0+NWS)   wsf[i] = C_SCALE * gWs[i - NW0];
    else if (i < NWTOT)     wsf[i] = C_SCALE * gWout[i - NW0 - NWS];
}

__global__ __launch_bounds__(256) void nnflow_kernel(
    const float4* __restrict__ xj4,
    const float* __restrict__ wsf,
    float4* __restrict__ out4,
    int nquads)
{
    int t = blockIdx.x * blockDim.x + threadIdx.x;
    if (t >= nquads) return;

    // ---- scaled weights: uniform address + const idx -> scalar loads ----
    float w0[DH][D];
    #pragma unroll
    for (int k = 0; k < DH; ++k)
        #pragma unroll
        for (int j = 0; j < D; ++j)
            w0[k][j] = wsf[k * D + j];

    float ws[NH][DH][DH];
    #pragma unroll
    for (int i = 0; i < NH; ++i)
        #pragma unroll
        for (int k = 0; k < DH; ++k)
            #pragma unroll
            for (int j = 0; j < DH; ++j)
                ws[i][k][j] = wsf[NW0 + (i * DH + k) * DH + j];

    float wo[D][DH];
    #pragma unroll
    for (int r = 0; r < D; ++r)
        #pragma unroll
        for (int j = 0; j < DH; ++j)
            wo[r][j] = wsf[NW0 + NWS + r * DH + j];

    // ---- 4 samples = 3 float4, coalesced; pack as 2 sample-pairs ----
    float4 v0 = xj4[(size_t)t * 3 + 0];
    float4 v1 = xj4[(size_t)t * 3 + 1];
    float4 v2 = xj4[(size_t)t * 3 + 2];

    v2f px0[2], px1[2], plj[2];
    px0[0].x = v0.x; px0[0].y = v0.w;  px0[1].x = v1.z; px0[1].y = v2.y;
    px1[0].x = v0.y; px1[0].y = v1.x;  px1[1].x = v1.w; px1[1].y = v2.z;
    plj[0].x = v0.z; plj[0].y = v1.y;  plj[1].x = v2.x; plj[1].y = v2.w;

    v2f ry0[2], ry1[2], rld[2];

    #pragma unroll
    for (int p = 0; p < 2; ++p) {
        v2f x0 = px0[p], x1 = px1[p];

        // ---- layer 0 ----
        v2f h[DH], J0[DH], J1[DH];
        #pragma unroll
        for (int k = 0; k < DH; ++k) {
            v2f z = vfma(splat(w0[k][0]), x0, splat(w0[k][1]) * x1);
            v2f hk, dk;
            act2(z, hk, dk);
            h[k]  = hk;
            J0[k] = splat(w0[k][0]) * dk;
            J1[k] = splat(w0[k][1]) * dk;
        }

        // ---- hidden layers ----
        #pragma unroll
        for (int i = 0; i < NH; ++i) {
            v2f hn[DH], Jn0[DH], Jn1[DH];
            #pragma unroll
            for (int k = 0; k < DH; ++k) {
                v2f z  = splat(ws[i][k][0]) * h[0];
                v2f j0 = splat(ws[i][k][0]) * J0[0];
                v2f j1 = splat(ws[i][k][0]) * J1[0];
                #pragma unroll
                for (int j = 1; j < DH; ++j) {
                    v2f w = splat(ws[i][k][j]);
                    z  = vfma(w, h[j],  z);
                    j0 = vfma(w, J0[j], j0);
                    j1 = vfma(w, J1[j], j1);
                }
                v2f hk, dk;
                act2(z, hk, dk);
                hn[k]  = hk;
                Jn0[k] = dk * j0;
                Jn1[k] = dk * j1;
            }
            #pragma unroll
            for (int k = 0; k < DH; ++k) { h[k] = hn[k]; J0[k] = Jn0[k]; J1[k] = Jn1[k]; }
        }

        // ---- output layer ----
        v2f y[2], dpv[2], o0[2], o1[2];
        #pragma unroll
        for (int r = 0; r < 2; ++r) {
            v2f z  = splat(wo[r][0]) * h[0];
            v2f j0 = splat(wo[r][0]) * J0[0];
            v2f j1 = splat(wo[r][0]) * J1[0];
            #pragma unroll
            for (int j = 1; j < DH; ++j) {
                v2f w = splat(wo[r][j]);
                z  = vfma(w, h[j],  z);
                j0 = vfma(w, J0[j], j0);
                j1 = vfma(w, J1[j], j1);
            }
            v2f yk, dk;
            act2(z, yk, dk);
            y[r] = yk; dpv[r] = dk;
            o0[r] = j0; o1[r] = j1;
        }

        // det = d0'*d1'*(o0[0]*o1[1] - o1[0]*o0[1])  (c^2 cancels exactly)
        v2f cross = vfma(-o1[0], o0[1], o0[0] * o1[1]);
        v2f det   = (dpv[0] * dpv[1]) * cross;
        v2f lg;
        lg.x = __builtin_amdgcn_logf(fabsf(det.x));
        lg.y = __builtin_amdgcn_logf(fabsf(det.y));
        rld[p] = vfma(splat(LN2), lg, plj[p]);
        ry0[p] = y[0];
        ry1[p] = y[1];
    }

    // ---- assemble 12 floats -> 3 float4 stores ----
    out4[(size_t)t * 3 + 0] = make_float4(ry0[0].x, ry1[0].x, rld[0].x, ry0[0].y);
    out4[(size_t)t * 3 + 1] = make_float4(ry1[0].y, rld[0].y, ry0[1].x, ry1[1].x);
    out4[(size_t)t * 3 + 2] = make_float4(rld[1].x, ry0[1].y, ry1[1].y, rld[1].y);
}

extern "C" void kernel_launch(void* const* d_in, const int* in_sizes, int n_in,
                              void* d_out, int out_size, void* d_ws, size_t ws_size,
                              hipStream_t stream) {
    const float* xj   = (const float*)d_in[0];
    const float* W0   = (const float*)d_in[1];
    const float* Ws   = (const float*)d_in[2];
    const float* Wout = (const float*)d_in[3];
    float* out = (float*)d_out;
    float* wsf = (float*)d_ws;

    prescale_kernel<<<1, 128, 0, stream>>>(W0, Ws, Wout, wsf);

    int n = in_sizes[0] / (D + 1);   // 4194304
    int nquads = n / 4;

    dim3 block(256);
    dim3 grid((nquads + block.x - 1) / block.x);
    nnflow_kernel<<<grid, block, 0, stream>>>(
        (const float4*)xj, wsf, (float4*)out, nquads);
}